// Round 3
// baseline (1052.909 us; speedup 1.0000x reference)
//
#include <hip/hip_runtime.h>
#include <hip/hip_bf16.h>
#include <cstdint>
#include <cstddef>

// ---- bf16-as-ushort helpers ----
// Inputs are fp32 holding bf16-rounded values -> truncation to bf16 is EXACT.
__device__ __forceinline__ unsigned short f2bs_trunc(float f){
  return (unsigned short)(__float_as_uint(f) >> 16);
}
__device__ __forceinline__ unsigned short f2bs(float f){
  __hip_bfloat16 h = __float2bfloat16(f);   // RNE, for computed values
  return *(unsigned short*)&h;
}
__device__ __forceinline__ float bflo(unsigned int u){ return __uint_as_float(u << 16); }
__device__ __forceinline__ float bfhi(unsigned int u){ return __uint_as_float(u & 0xffff0000u); }
__device__ __forceinline__ float bf2f(unsigned short u){
  return __uint_as_float(((unsigned int)u) << 16);
}

// ---------------- CSR build (per call; graph is an input) ----------------
__global__ void zero_int_kernel(int* __restrict__ p, int n){
  int i = blockIdx.x*256 + threadIdx.x;
  if (i < n) p[i] = 0;
}

__global__ void hist_kernel(const int* __restrict__ dst, int E, int* __restrict__ deg){
  int e = blockIdx.x*256 + threadIdx.x;
  if (e < E) atomicAdd(&deg[dst[e]], 1);
}

__global__ __launch_bounds__(1024)
void scanA_kernel(const int* __restrict__ deg, int n, int* __restrict__ rowptr, int* __restrict__ bsums){
  __shared__ int s[1024];
  int t = threadIdx.x;
  int i = blockIdx.x*1024 + t;
  int v = (i < n) ? deg[i] : 0;
  s[t] = v;
  __syncthreads();
  #pragma unroll
  for (int off = 1; off < 1024; off <<= 1){
    int a = (t >= off) ? s[t-off] : 0;
    __syncthreads();
    s[t] += a;
    __syncthreads();
  }
  if (i < n) rowptr[i] = s[t] - v;      // chunk-local exclusive
  if (t == 1023) bsums[blockIdx.x] = s[1023];
}

__global__ void scanB_kernel(const int* __restrict__ bsums, int nch, int* __restrict__ choff){
  int t = threadIdx.x;                   // 64 threads; nch <= 64 (49 here)
  int v = (t < nch) ? bsums[t] : 0;
  int x = v;
  #pragma unroll
  for (int off = 1; off < 64; off <<= 1){
    int u = __shfl_up(x, off, 64);
    if (t >= off) x += u;
  }
  choff[t] = x - v;                      // exclusive
}

__global__ __launch_bounds__(1024)
void scanC_kernel(const int* __restrict__ choff, int n, int* __restrict__ rowptr, int* __restrict__ cursor){
  int i = blockIdx.x*1024 + threadIdx.x;
  if (i < n){
    int r = rowptr[i] + choff[blockIdx.x];
    rowptr[i] = r;
    cursor[i] = r;
  }
}

__global__ void scatter_kernel(const int* __restrict__ src, const int* __restrict__ dst, int E,
                               int* __restrict__ cursor, int* __restrict__ adj){
  int e = blockIdx.x*256 + threadIdx.x;
  if (e < E){
    int pos = atomicAdd(&cursor[dst[e]], 1);
    adj[pos] = src[e];
  }
}

// ---------------- Fused 4-way projection GEMM ----------------
// blockIdx.y = msel in {q,k,v,skip}; 64-node x 128-col tile per block.
// W fp32 [DIN][128] input -> staged bf16 in LDS (lossless: values bf16-grid).
// X loaded directly from global (16 lanes broadcast per address).
// All four outputs written bf16.
template<int DIN, typename XT>
__global__ __launch_bounds__(256)
void gemm4_kernel(const XT* __restrict__ X, int nn,
                  const float* __restrict__ Wq, const float* __restrict__ Wk,
                  const float* __restrict__ Wv, const float* __restrict__ Ws,
                  const float* __restrict__ bq, const float* __restrict__ bk,
                  const float* __restrict__ bv, const float* __restrict__ bs,
                  unsigned short* __restrict__ Oq, unsigned short* __restrict__ Ok,
                  unsigned short* __restrict__ Ov, unsigned short* __restrict__ Os)
{
  __shared__ __align__(16) unsigned short wsh[DIN][128];
  int t = threadIdx.x;
  int msel = blockIdx.y;
  const float* W = (msel==0)?Wq:(msel==1)?Wk:(msel==2)?Wv:Ws;
  const float* B = (msel==0)?bq:(msel==1)?bk:(msel==2)?bv:bs;
  unsigned short* O = (msel==0)?Oq:(msel==1)?Ok:(msel==2)?Ov:Os;

  { // stage W: fp32 global -> bf16 LDS (exact truncation)
    const int U = DIN*128/4;             // float4 chunks
    const float4* Wsrc = (const float4*)W;
    ushort4* Wdst = (ushort4*)&wsh[0][0];
    for (int u = t; u < U; u += 256){
      float4 w4 = Wsrc[u];
      ushort4 s4;
      s4.x = f2bs_trunc(w4.x); s4.y = f2bs_trunc(w4.y);
      s4.z = f2bs_trunc(w4.z); s4.w = f2bs_trunc(w4.w);
      Wdst[u] = s4;
    }
  }
  __syncthreads();

  int tx = t & 15;                       // col octet: j = tx*8..+7
  int ty = t >> 4;                       // node quad: rows ty*4..+3
  int base = blockIdx.x * 64;
  int  row[4];
  bool ok[4];
  #pragma unroll
  for (int i=0;i<4;i++){ row[i] = base + ty*4 + i; ok[i] = row[i] < nn; }

  float acc[4][8];
  #pragma unroll
  for (int i=0;i<4;i++){
    #pragma unroll
    for (int j=0;j<8;j++) acc[i][j]=0.f;
  }

  for (int o = 0; o < DIN/8; o++){
    // X fragment: 4 rows x 8 k's, direct from global (broadcast across tx)
    float xf[4][8];
    #pragma unroll
    for (int i=0;i<4;i++){
      if constexpr (sizeof(XT) == 2){    // bf16 rows
        uint4 c = {0u,0u,0u,0u};
        if (ok[i]) c = *(const uint4*)((const unsigned short*)X + (size_t)row[i]*DIN + o*8);
        xf[i][0]=bflo(c.x); xf[i][1]=bfhi(c.x);
        xf[i][2]=bflo(c.y); xf[i][3]=bfhi(c.y);
        xf[i][4]=bflo(c.z); xf[i][5]=bfhi(c.z);
        xf[i][6]=bflo(c.w); xf[i][7]=bfhi(c.w);
      } else {                           // fp32 rows
        float4 a = {0.f,0.f,0.f,0.f}, b = {0.f,0.f,0.f,0.f};
        if (ok[i]){
          a = *(const float4*)((const float*)X + (size_t)row[i]*DIN + o*8);
          b = *(const float4*)((const float*)X + (size_t)row[i]*DIN + o*8 + 4);
        }
        xf[i][0]=a.x; xf[i][1]=a.y; xf[i][2]=a.z; xf[i][3]=a.w;
        xf[i][4]=b.x; xf[i][5]=b.y; xf[i][6]=b.z; xf[i][7]=b.w;
      }
    }
    #pragma unroll
    for (int jj=0; jj<8; jj++){
      int kk = o*8 + jj;
      uint4 w = *(const uint4*)&wsh[kk][tx*8];
      float wf[8];
      wf[0]=bflo(w.x); wf[1]=bfhi(w.x);
      wf[2]=bflo(w.y); wf[3]=bfhi(w.y);
      wf[4]=bflo(w.z); wf[5]=bfhi(w.z);
      wf[6]=bflo(w.w); wf[7]=bfhi(w.w);
      #pragma unroll
      for (int i=0;i<4;i++){
        float xv = xf[i][jj];
        #pragma unroll
        for (int j=0;j<8;j++) acc[i][j] = fmaf(xv, wf[j], acc[i][j]);
      }
    }
  }

  float bvv[8];
  #pragma unroll
  for (int j=0;j<8;j++) bvv[j] = B[tx*8+j];

  #pragma unroll
  for (int i=0;i<4;i++){
    if (ok[i]){
      float r[8];
      #pragma unroll
      for (int j=0;j<8;j++) r[j] = acc[i][j] + bvv[j];
      uint4 st;
      st.x = (unsigned int)f2bs(r[0]) | ((unsigned int)f2bs(r[1])<<16);
      st.y = (unsigned int)f2bs(r[2]) | ((unsigned int)f2bs(r[3])<<16);
      st.z = (unsigned int)f2bs(r[4]) | ((unsigned int)f2bs(r[5])<<16);
      st.w = (unsigned int)f2bs(r[6]) | ((unsigned int)f2bs(r[7])<<16);
      *(uint4*)(O + (size_t)row[i]*128 + tx*8) = st;
    }
  }
}

// ---------------- Per-node attention (wave = one destination node) ----------------
// Lane holds channels c = 2*lane, 2*lane+1  -> head = lane>>4.
// Flash-style chunked online softmax (chunk = 64 edges); no atomics.
// q/k/v/skip bf16; hout bf16 (may alias skip: own-row access only).
__global__ __launch_bounds__(256)
void attn_kernel(const unsigned short* __restrict__ q,  const unsigned short* __restrict__ kmat,
                 const unsigned short* __restrict__ vmat, const unsigned short* __restrict__ skip,
                 const int* __restrict__ rowptr, const int* __restrict__ deg,
                 const int* __restrict__ adj, unsigned short* __restrict__ hout, int nn)
{
  __shared__ float sb_all[4][64*4];
  int lane = threadIdx.x & 63, wid = threadIdx.x >> 6;
  int n = blockIdx.x*4 + wid;
  if (n >= nn) return;                   // wave-uniform; no block barriers used
  float* sb = sb_all[wid];
  const float RS = 0.17677669529663687f; // 1/sqrt(32)

  unsigned int qu = *(const unsigned int*)(q + (size_t)n*128 + 2*lane);
  float qx = bflo(qu), qy = bfhi(qu);
  int start = rowptr[n], dg = deg[n];
  int hh = lane >> 4;                    // this lane's head
  float m[4] = {-INFINITY,-INFINITY,-INFINITY,-INFINITY};
  float l[4] = {0.f,0.f,0.f,0.f};
  float accx = 0.f, accy = 0.f;

  for (int c0 = 0; c0 < dg; c0 += 64){
    int cn = min(64, dg - c0);
    // --- score pass: wave cooperates per edge; 4 head-dots via 16-lane butterflies
    for (int j = 0; j < cn; j++){
      int s = adj[start + c0 + j];
      unsigned int ku = *(const unsigned int*)(kmat + (size_t)s*128 + 2*lane);
      float p = qx*bflo(ku) + qy*bfhi(ku);
      #pragma unroll
      for (int msk = 1; msk <= 8; msk <<= 1) p += __shfl_xor(p, msk, 64);
      if ((lane & 15) == 0) sb[j*4 + hh] = p * RS;
    }
    // --- chunk max / weights / sums (lane j owns edge j)
    float s4[4];
    if (lane < cn){
      s4[0]=sb[lane*4+0]; s4[1]=sb[lane*4+1]; s4[2]=sb[lane*4+2]; s4[3]=sb[lane*4+3];
    } else { s4[0]=s4[1]=s4[2]=s4[3]=-INFINITY; }
    float cm[4] = {s4[0],s4[1],s4[2],s4[3]};
    #pragma unroll
    for (int msk = 1; msk <= 32; msk <<= 1){
      #pragma unroll
      for (int h=0; h<4; h++) cm[h] = fmaxf(cm[h], __shfl_xor(cm[h], msk, 64));
    }
    float r[4], w4[4];
    #pragma unroll
    for (int h=0; h<4; h++){
      float nm = fmaxf(m[h], cm[h]);     // cm finite (cn>=1) -> nm finite
      r[h] = __expf(m[h] - nm);          // first chunk: exp(-inf)=0, safe
      l[h] *= r[h];
      m[h] = nm;
      w4[h] = (lane < cn) ? __expf(s4[h] - nm) : 0.f;
    }
    accx *= r[hh]; accy *= r[hh];
    if (lane < cn){
      sb[lane*4+0]=w4[0]; sb[lane*4+1]=w4[1]; sb[lane*4+2]=w4[2]; sb[lane*4+3]=w4[3];
    }
    float cs[4] = {w4[0],w4[1],w4[2],w4[3]};
    #pragma unroll
    for (int msk = 1; msk <= 32; msk <<= 1){
      #pragma unroll
      for (int h=0; h<4; h++) cs[h] += __shfl_xor(cs[h], msk, 64);
    }
    #pragma unroll
    for (int h=0; h<4; h++) l[h] += cs[h];
    // --- aggregation pass
    for (int j = 0; j < cn; j++){
      int s = adj[start + c0 + j];
      float wl = sb[j*4 + hh];
      unsigned int vu = *(const unsigned int*)(vmat + (size_t)s*128 + 2*lane);
      accx = fmaf(wl, bflo(vu), accx);
      accy = fmaf(wl, bfhi(vu), accy);
    }
  }

  float li = l[hh];
  float inv = (li > 0.f) ? 1.f/li : 0.f; // deg==0 -> agg 0, matches reference
  unsigned int su = *(const unsigned int*)(skip + (size_t)n*128 + 2*lane);
  float ox = fmaxf(fmaf(accx, inv, bflo(su)), 0.f);
  float oy = fmaxf(fmaf(accy, inv, bfhi(su)), 0.f);
  unsigned int pk = (unsigned int)f2bs(ox) | ((unsigned int)f2bs(oy) << 16);
  *(unsigned int*)(hout + (size_t)n*128 + 2*lane) = pk; // own row; alias-safe
}

// ---------------- Output head: sigmoid(h @ Wf + bf); h bf16, Wf/bf fp32, out fp32 ----------------
__global__ __launch_bounds__(256)
void head_kernel(const unsigned short* __restrict__ h, const float* __restrict__ Wf,
                 const float* __restrict__ bfp, float* __restrict__ out, int nn)
{
  int lane = threadIdx.x & 63, wid = threadIdx.x >> 6;
  int n = blockIdx.x*4 + wid;
  if (n >= nn) return;
  unsigned int hu = *(const unsigned int*)(h + (size_t)n*128 + 2*lane);
  float2 wv = *(const float2*)(Wf + 2*lane);
  float p = bflo(hu)*wv.x + bfhi(hu)*wv.y;
  #pragma unroll
  for (int msk = 1; msk <= 32; msk <<= 1) p += __shfl_xor(p, msk, 64);
  if (lane == 0){
    float z = p + bfp[0];
    out[n] = 1.f / (1.f + __expf(-z));
  }
}

// ---------------- Launch ----------------
extern "C" void kernel_launch(void* const* d_in, const int* in_sizes, int n_in,
                              void* d_out, int out_size, void* d_ws, size_t ws_size,
                              hipStream_t stream) {
  const int N = in_sizes[0] / 32;
  const int E = in_sizes[1] / 2;
  const float* x = (const float*)d_in[0];       // fp32 (bf16-rounded values)
  const int* ei  = (const int*)d_in[1];
  const int* src = ei;
  const int* dst = ei + E;
  auto Wp = [&](int i){ return (const float*)d_in[i]; };

  // workspace carve: 5 bf16 node buffers (12.8 MB each) + CSR  (~68 MB)
  char* p = (char*)d_ws;
  auto alloc = [&](size_t b){ char* r = p; p += (b + 255) & ~(size_t)255; return (void*)r; };
  unsigned short* F0 = (unsigned short*)alloc((size_t)N*128*2);
  unsigned short* F1 = (unsigned short*)alloc((size_t)N*128*2);
  unsigned short* Qb = (unsigned short*)alloc((size_t)N*128*2);
  unsigned short* Kb = (unsigned short*)alloc((size_t)N*128*2);
  unsigned short* Vb = (unsigned short*)alloc((size_t)N*128*2);
  int* deg    = (int*)alloc((size_t)N*4);
  int* rowptr = (int*)alloc((size_t)N*4);
  int* cursor = (int*)alloc((size_t)N*4);
  int* adj    = (int*)alloc((size_t)E*4);
  int* bsums  = (int*)alloc(64*4);
  int* choff  = (int*)alloc(64*4);

  // CSR build
  zero_int_kernel<<<(N+255)/256, 256, 0, stream>>>(deg, N);
  hist_kernel<<<(E+255)/256, 256, 0, stream>>>(dst, E, deg);
  int nch = (N + 1023) / 1024;
  scanA_kernel<<<nch, 1024, 0, stream>>>(deg, N, rowptr, bsums);
  scanB_kernel<<<1, 64, 0, stream>>>(bsums, nch, choff);
  scanC_kernel<<<nch, 1024, 0, stream>>>(choff, N, rowptr, cursor);
  scatter_kernel<<<(E+255)/256, 256, 0, stream>>>(src, dst, E, cursor, adj);

  dim3 gg((N+63)/64, 4);
  int ab = (N + 3) / 4;
  // layer 0 (din=32, X = fp32 input x): skip -> F0; attn in-place on F0
  gemm4_kernel<32, float><<<gg, 256, 0, stream>>>(x, N,
      Wp(2),Wp(4),Wp(6),Wp(8), Wp(3),Wp(5),Wp(7),Wp(9), Qb,Kb,Vb, F0);
  attn_kernel<<<ab, 256, 0, stream>>>(Qb,Kb,Vb, F0, rowptr,deg,adj, F0, N);
  // layer 1 (din=128, X = F0 bf16): skip -> F1; attn in-place on F1
  gemm4_kernel<128, unsigned short><<<gg, 256, 0, stream>>>(F0, N,
      Wp(10),Wp(12),Wp(14),Wp(16), Wp(11),Wp(13),Wp(15),Wp(17), Qb,Kb,Vb, F1);
  attn_kernel<<<ab, 256, 0, stream>>>(Qb,Kb,Vb, F1, rowptr,deg,adj, F1, N);
  // layer 2 (din=128, X = F1 bf16): skip -> F0; attn in-place on F0
  gemm4_kernel<128, unsigned short><<<gg, 256, 0, stream>>>(F1, N,
      Wp(18),Wp(20),Wp(22),Wp(24), Wp(19),Wp(21),Wp(23),Wp(25), Qb,Kb,Vb, F0);
  attn_kernel<<<ab, 256, 0, stream>>>(Qb,Kb,Vb, F0, rowptr,deg,adj, F0, N);
  // head
  head_kernel<<<ab, 256, 0, stream>>>(F0, Wp(26), Wp(27), (float*)d_out, N);
}

// Round 4
// 652.391 us; speedup vs baseline: 1.6139x; 1.6139x over previous
//
#include <hip/hip_runtime.h>
#include <hip/hip_bf16.h>
#include <cstdint>
#include <cstddef>

// ---- bf16-as-ushort helpers ----
// Inputs are fp32 holding bf16-rounded values -> truncation to bf16 is EXACT.
__device__ __forceinline__ unsigned short f2bs_trunc(float f){
  return (unsigned short)(__float_as_uint(f) >> 16);
}
__device__ __forceinline__ unsigned short f2bs(float f){
  __hip_bfloat16 h = __float2bfloat16(f);   // RNE, for computed values
  return *(unsigned short*)&h;
}
__device__ __forceinline__ float bflo(unsigned int u){ return __uint_as_float(u << 16); }
__device__ __forceinline__ float bfhi(unsigned int u){ return __uint_as_float(u & 0xffff0000u); }
__device__ __forceinline__ float bf2f(unsigned short u){
  return __uint_as_float(((unsigned int)u) << 16);
}

// ---------------- CSR build (per call; graph is an input) ----------------
__global__ void zero_int_kernel(int* __restrict__ p, int n){
  int i = blockIdx.x*256 + threadIdx.x;
  if (i < n) p[i] = 0;
}

__global__ void hist_kernel(const int* __restrict__ dst, int E, int* __restrict__ deg){
  int e = blockIdx.x*256 + threadIdx.x;
  if (e < E) atomicAdd(&deg[dst[e]], 1);
}

__global__ __launch_bounds__(1024)
void scanA_kernel(const int* __restrict__ deg, int n, int* __restrict__ rowptr, int* __restrict__ bsums){
  __shared__ int s[1024];
  int t = threadIdx.x;
  int i = blockIdx.x*1024 + t;
  int v = (i < n) ? deg[i] : 0;
  s[t] = v;
  __syncthreads();
  #pragma unroll
  for (int off = 1; off < 1024; off <<= 1){
    int a = (t >= off) ? s[t-off] : 0;
    __syncthreads();
    s[t] += a;
    __syncthreads();
  }
  if (i < n) rowptr[i] = s[t] - v;      // chunk-local exclusive
  if (t == 1023) bsums[blockIdx.x] = s[1023];
}

__global__ void scanB_kernel(const int* __restrict__ bsums, int nch, int* __restrict__ choff){
  int t = threadIdx.x;                   // 64 threads; nch <= 64 (49 here)
  int v = (t < nch) ? bsums[t] : 0;
  int x = v;
  #pragma unroll
  for (int off = 1; off < 64; off <<= 1){
    int u = __shfl_up(x, off, 64);
    if (t >= off) x += u;
  }
  choff[t] = x - v;                      // exclusive
}

__global__ __launch_bounds__(1024)
void scanC_kernel(const int* __restrict__ choff, int n, int* __restrict__ rowptr, int* __restrict__ cursor){
  int i = blockIdx.x*1024 + threadIdx.x;
  if (i < n){
    int r = rowptr[i] + choff[blockIdx.x];
    rowptr[i] = r;
    cursor[i] = r;
  }
}

__global__ void scatter_kernel(const int* __restrict__ src, const int* __restrict__ dst, int E,
                               int* __restrict__ cursor, int* __restrict__ adj){
  int e = blockIdx.x*256 + threadIdx.x;
  if (e < E){
    int pos = atomicAdd(&cursor[dst[e]], 1);
    adj[pos] = src[e];
  }
}

// ---------------- Fused 4-way projection GEMM ----------------
// blockIdx.y = msel in {q,k,v,skip}; 64-node x 128-col tile per block.
// W fp32 [DIN][128] input -> staged bf16 in LDS (lossless: values bf16-grid).
// X loaded directly from global (16 lanes broadcast per address).
// All four outputs written bf16.
template<int DIN, typename XT>
__global__ __launch_bounds__(256)
void gemm4_kernel(const XT* __restrict__ X, int nn,
                  const float* __restrict__ Wq, const float* __restrict__ Wk,
                  const float* __restrict__ Wv, const float* __restrict__ Ws,
                  const float* __restrict__ bq, const float* __restrict__ bk,
                  const float* __restrict__ bv, const float* __restrict__ bs,
                  unsigned short* __restrict__ Oq, unsigned short* __restrict__ Ok,
                  unsigned short* __restrict__ Ov, unsigned short* __restrict__ Os)
{
  __shared__ __align__(16) unsigned short wsh[DIN][128];
  int t = threadIdx.x;
  int msel = blockIdx.y;
  const float* W = (msel==0)?Wq:(msel==1)?Wk:(msel==2)?Wv:Ws;
  const float* B = (msel==0)?bq:(msel==1)?bk:(msel==2)?bv:bs;
  unsigned short* O = (msel==0)?Oq:(msel==1)?Ok:(msel==2)?Ov:Os;

  { // stage W: fp32 global -> bf16 LDS (exact truncation)
    const int U = DIN*128/4;             // float4 chunks
    const float4* Wsrc = (const float4*)W;
    ushort4* Wdst = (ushort4*)&wsh[0][0];
    for (int u = t; u < U; u += 256){
      float4 w4 = Wsrc[u];
      ushort4 s4;
      s4.x = f2bs_trunc(w4.x); s4.y = f2bs_trunc(w4.y);
      s4.z = f2bs_trunc(w4.z); s4.w = f2bs_trunc(w4.w);
      Wdst[u] = s4;
    }
  }
  __syncthreads();

  int tx = t & 15;                       // col octet: j = tx*8..+7
  int ty = t >> 4;                       // node quad: rows ty*4..+3
  int base = blockIdx.x * 64;
  int  row[4];
  bool ok[4];
  #pragma unroll
  for (int i=0;i<4;i++){ row[i] = base + ty*4 + i; ok[i] = row[i] < nn; }

  float acc[4][8];
  #pragma unroll
  for (int i=0;i<4;i++){
    #pragma unroll
    for (int j=0;j<8;j++) acc[i][j]=0.f;
  }

  for (int o = 0; o < DIN/8; o++){
    // X fragment: 4 rows x 8 k's, direct from global (broadcast across tx)
    float xf[4][8];
    #pragma unroll
    for (int i=0;i<4;i++){
      if constexpr (sizeof(XT) == 2){    // bf16 rows
        uint4 c = {0u,0u,0u,0u};
        if (ok[i]) c = *(const uint4*)((const unsigned short*)X + (size_t)row[i]*DIN + o*8);
        xf[i][0]=bflo(c.x); xf[i][1]=bfhi(c.x);
        xf[i][2]=bflo(c.y); xf[i][3]=bfhi(c.y);
        xf[i][4]=bflo(c.z); xf[i][5]=bfhi(c.z);
        xf[i][6]=bflo(c.w); xf[i][7]=bfhi(c.w);
      } else {                           // fp32 rows
        float4 a = {0.f,0.f,0.f,0.f}, b = {0.f,0.f,0.f,0.f};
        if (ok[i]){
          a = *(const float4*)((const float*)X + (size_t)row[i]*DIN + o*8);
          b = *(const float4*)((const float*)X + (size_t)row[i]*DIN + o*8 + 4);
        }
        xf[i][0]=a.x; xf[i][1]=a.y; xf[i][2]=a.z; xf[i][3]=a.w;
        xf[i][4]=b.x; xf[i][5]=b.y; xf[i][6]=b.z; xf[i][7]=b.w;
      }
    }
    #pragma unroll
    for (int jj=0; jj<8; jj++){
      int kk = o*8 + jj;
      uint4 w = *(const uint4*)&wsh[kk][tx*8];
      float wf[8];
      wf[0]=bflo(w.x); wf[1]=bfhi(w.x);
      wf[2]=bflo(w.y); wf[3]=bfhi(w.y);
      wf[4]=bflo(w.z); wf[5]=bfhi(w.z);
      wf[6]=bflo(w.w); wf[7]=bfhi(w.w);
      #pragma unroll
      for (int i=0;i<4;i++){
        float xv = xf[i][jj];
        #pragma unroll
        for (int j=0;j<8;j++) acc[i][j] = fmaf(xv, wf[j], acc[i][j]);
      }
    }
  }

  float bvv[8];
  #pragma unroll
  for (int j=0;j<8;j++) bvv[j] = B[tx*8+j];

  #pragma unroll
  for (int i=0;i<4;i++){
    if (ok[i]){
      float r[8];
      #pragma unroll
      for (int j=0;j<8;j++) r[j] = acc[i][j] + bvv[j];
      uint4 st;
      st.x = (unsigned int)f2bs(r[0]) | ((unsigned int)f2bs(r[1])<<16);
      st.y = (unsigned int)f2bs(r[2]) | ((unsigned int)f2bs(r[3])<<16);
      st.z = (unsigned int)f2bs(r[4]) | ((unsigned int)f2bs(r[5])<<16);
      st.w = (unsigned int)f2bs(r[6]) | ((unsigned int)f2bs(r[7])<<16);
      *(uint4*)(O + (size_t)row[i]*128 + tx*8) = st;
    }
  }
}

// ---------------- Per-node attention, fused single pass ----------------
// Wave = one destination node. Lane holds channels c = 2*lane, 2*lane+1
// -> head = lane>>4. After the 16-lane butterfly every lane has its own
// head's score, so online-softmax state (m,l) is per-lane SCALAR.
// Edges processed in groups of 4: 8 independent row loads (k+v) issued
// up front -> high memory-level parallelism. No LDS, no atomics.
__global__ __launch_bounds__(256)
void attn_kernel(const unsigned short* __restrict__ q,  const unsigned short* __restrict__ kmat,
                 const unsigned short* __restrict__ vmat, const unsigned short* __restrict__ skip,
                 const int* __restrict__ rowptr, const int* __restrict__ deg,
                 const int* __restrict__ adj, unsigned short* __restrict__ hout, int nn)
{
  int lane = threadIdx.x & 63, wid = threadIdx.x >> 6;
  int n = blockIdx.x*4 + wid;
  if (n >= nn) return;                   // wave-uniform
  const float RS = 0.17677669529663687f; // 1/sqrt(32)

  unsigned int qu = *(const unsigned int*)(q + (size_t)n*128 + 2*lane);
  float qx = bflo(qu), qy = bfhi(qu);
  int start = rowptr[n], dg = deg[n];
  float m = -INFINITY, l = 0.f, accx = 0.f, accy = 0.f;

  for (int c0 = 0; c0 < dg; c0 += 64){
    int cn = min(64, dg - c0);
    // coalesced chunk adjacency load; clamp so every lane holds a valid edge
    int idx = adj[start + c0 + min(lane, cn-1)];

    for (int g = 0; g < cn; g += 4){
      int gm = cn - g;                   // >=1; group size = min(4, gm)
      int e0 = g;
      int e1 = min(g+1, cn-1);
      int e2 = min(g+2, cn-1);
      int e3 = min(g+3, cn-1);
      int s0 = __shfl(idx, e0, 64);
      int s1 = __shfl(idx, e1, 64);
      int s2 = __shfl(idx, e2, 64);
      int s3 = __shfl(idx, e3, 64);
      // 8 independent 4B/lane loads (each = one contiguous 256B row)
      unsigned int ku0 = *(const unsigned int*)(kmat + (size_t)s0*128 + 2*lane);
      unsigned int ku1 = *(const unsigned int*)(kmat + (size_t)s1*128 + 2*lane);
      unsigned int ku2 = *(const unsigned int*)(kmat + (size_t)s2*128 + 2*lane);
      unsigned int ku3 = *(const unsigned int*)(kmat + (size_t)s3*128 + 2*lane);
      unsigned int vu0 = *(const unsigned int*)(vmat + (size_t)s0*128 + 2*lane);
      unsigned int vu1 = *(const unsigned int*)(vmat + (size_t)s1*128 + 2*lane);
      unsigned int vu2 = *(const unsigned int*)(vmat + (size_t)s2*128 + 2*lane);
      unsigned int vu3 = *(const unsigned int*)(vmat + (size_t)s3*128 + 2*lane);

      float p0 = qx*bflo(ku0) + qy*bfhi(ku0);
      float p1 = qx*bflo(ku1) + qy*bfhi(ku1);
      float p2 = qx*bflo(ku2) + qy*bfhi(ku2);
      float p3 = qx*bflo(ku3) + qy*bfhi(ku3);
      #pragma unroll
      for (int msk = 1; msk <= 8; msk <<= 1){
        p0 += __shfl_xor(p0, msk, 64);
        p1 += __shfl_xor(p1, msk, 64);
        p2 += __shfl_xor(p2, msk, 64);
        p3 += __shfl_xor(p3, msk, 64);
      }
      // scores for this lane's head; dup/tail edges masked to -inf
      float f0 = p0*RS;
      float f1 = (gm > 1) ? p1*RS : -INFINITY;
      float f2 = (gm > 2) ? p2*RS : -INFINITY;
      float f3 = (gm > 3) ? p3*RS : -INFINITY;

      float gmax = fmaxf(fmaxf(f0,f1), fmaxf(f2,f3));
      float nm = fmaxf(m, gmax);         // finite (f0 finite)
      float r  = __expf(m - nm);         // first group: exp(-inf)=0
      float w0 = __expf(f0 - nm);
      float w1 = __expf(f1 - nm);        // -inf -> 0
      float w2 = __expf(f2 - nm);
      float w3 = __expf(f3 - nm);
      m = nm;
      l = l*r + ((w0+w1) + (w2+w3));
      accx = accx*r;
      accy = accy*r;
      accx = fmaf(w0, bflo(vu0), accx); accy = fmaf(w0, bfhi(vu0), accy);
      accx = fmaf(w1, bflo(vu1), accx); accy = fmaf(w1, bfhi(vu1), accy);
      accx = fmaf(w2, bflo(vu2), accx); accy = fmaf(w2, bfhi(vu2), accy);
      accx = fmaf(w3, bflo(vu3), accx); accy = fmaf(w3, bfhi(vu3), accy);
    }
  }

  float inv = (l > 0.f) ? 1.f/l : 0.f;   // deg==0 -> agg 0, matches reference
  unsigned int su = *(const unsigned int*)(skip + (size_t)n*128 + 2*lane);
  float ox = fmaxf(fmaf(accx, inv, bflo(su)), 0.f);
  float oy = fmaxf(fmaf(accy, inv, bfhi(su)), 0.f);
  unsigned int pk = (unsigned int)f2bs(ox) | ((unsigned int)f2bs(oy) << 16);
  *(unsigned int*)(hout + (size_t)n*128 + 2*lane) = pk; // own row; alias-safe
}

// ---------------- Output head: sigmoid(h @ Wf + bf); h bf16, Wf/bf fp32, out fp32 ----------------
__global__ __launch_bounds__(256)
void head_kernel(const unsigned short* __restrict__ h, const float* __restrict__ Wf,
                 const float* __restrict__ bfp, float* __restrict__ out, int nn)
{
  int lane = threadIdx.x & 63, wid = threadIdx.x >> 6;
  int n = blockIdx.x*4 + wid;
  if (n >= nn) return;
  unsigned int hu = *(const unsigned int*)(h + (size_t)n*128 + 2*lane);
  float2 wv = *(const float2*)(Wf + 2*lane);
  float p = bflo(hu)*wv.x + bfhi(hu)*wv.y;
  #pragma unroll
  for (int msk = 1; msk <= 32; msk <<= 1) p += __shfl_xor(p, msk, 64);
  if (lane == 0){
    float z = p + bfp[0];
    out[n] = 1.f / (1.f + __expf(-z));
  }
}

// ---------------- Launch ----------------
extern "C" void kernel_launch(void* const* d_in, const int* in_sizes, int n_in,
                              void* d_out, int out_size, void* d_ws, size_t ws_size,
                              hipStream_t stream) {
  const int N = in_sizes[0] / 32;
  const int E = in_sizes[1] / 2;
  const float* x = (const float*)d_in[0];       // fp32 (bf16-rounded values)
  const int* ei  = (const int*)d_in[1];
  const int* src = ei;
  const int* dst = ei + E;
  auto Wp = [&](int i){ return (const float*)d_in[i]; };

  // workspace carve: 5 bf16 node buffers (12.8 MB each) + CSR  (~68 MB)
  char* p = (char*)d_ws;
  auto alloc = [&](size_t b){ char* r = p; p += (b + 255) & ~(size_t)255; return (void*)r; };
  unsigned short* F0 = (unsigned short*)alloc((size_t)N*128*2);
  unsigned short* F1 = (unsigned short*)alloc((size_t)N*128*2);
  unsigned short* Qb = (unsigned short*)alloc((size_t)N*128*2);
  unsigned short* Kb = (unsigned short*)alloc((size_t)N*128*2);
  unsigned short* Vb = (unsigned short*)alloc((size_t)N*128*2);
  int* deg    = (int*)alloc((size_t)N*4);
  int* rowptr = (int*)alloc((size_t)N*4);
  int* cursor = (int*)alloc((size_t)N*4);
  int* adj    = (int*)alloc((size_t)E*4);
  int* bsums  = (int*)alloc(64*4);
  int* choff  = (int*)alloc(64*4);

  // CSR build
  zero_int_kernel<<<(N+255)/256, 256, 0, stream>>>(deg, N);
  hist_kernel<<<(E+255)/256, 256, 0, stream>>>(dst, E, deg);
  int nch = (N + 1023) / 1024;
  scanA_kernel<<<nch, 1024, 0, stream>>>(deg, N, rowptr, bsums);
  scanB_kernel<<<1, 64, 0, stream>>>(bsums, nch, choff);
  scanC_kernel<<<nch, 1024, 0, stream>>>(choff, N, rowptr, cursor);
  scatter_kernel<<<(E+255)/256, 256, 0, stream>>>(src, dst, E, cursor, adj);

  dim3 gg((N+63)/64, 4);
  int ab = (N + 3) / 4;
  // layer 0 (din=32, X = fp32 input x): skip -> F0; attn in-place on F0
  gemm4_kernel<32, float><<<gg, 256, 0, stream>>>(x, N,
      Wp(2),Wp(4),Wp(6),Wp(8), Wp(3),Wp(5),Wp(7),Wp(9), Qb,Kb,Vb, F0);
  attn_kernel<<<ab, 256, 0, stream>>>(Qb,Kb,Vb, F0, rowptr,deg,adj, F0, N);
  // layer 1 (din=128, X = F0 bf16): skip -> F1; attn in-place on F1
  gemm4_kernel<128, unsigned short><<<gg, 256, 0, stream>>>(F0, N,
      Wp(10),Wp(12),Wp(14),Wp(16), Wp(11),Wp(13),Wp(15),Wp(17), Qb,Kb,Vb, F1);
  attn_kernel<<<ab, 256, 0, stream>>>(Qb,Kb,Vb, F1, rowptr,deg,adj, F1, N);
  // layer 2 (din=128, X = F1 bf16): skip -> F0; attn in-place on F0
  gemm4_kernel<128, unsigned short><<<gg, 256, 0, stream>>>(F1, N,
      Wp(18),Wp(20),Wp(22),Wp(24), Wp(19),Wp(21),Wp(23),Wp(25), Qb,Kb,Vb, F0);
  attn_kernel<<<ab, 256, 0, stream>>>(Qb,Kb,Vb, F0, rowptr,deg,adj, F0, N);
  // head
  head_kernel<<<ab, 256, 0, stream>>>(F0, Wp(26), Wp(27), (float*)d_out, N);
}

// Round 5
// 482.554 us; speedup vs baseline: 2.1819x; 1.3520x over previous
//
#include <hip/hip_runtime.h>
#include <hip/hip_bf16.h>
#include <cstdint>
#include <cstddef>

typedef __attribute__((ext_vector_type(8))) short bf16x8;   // 8 bf16 = 4 VGPRs
typedef __attribute__((ext_vector_type(4))) float f32x4;    // MFMA acc

// ---- bf16-as-ushort helpers ----
__device__ __forceinline__ unsigned short f2bs(float f){
  __hip_bfloat16 h = __float2bfloat16(f);   // RNE
  return *(unsigned short*)&h;
}
__device__ __forceinline__ float bflo(unsigned int u){ return __uint_as_float(u << 16); }
__device__ __forceinline__ float bfhi(unsigned int u){ return __uint_as_float(u & 0xffff0000u); }

// ---------------- CSR build (per call; graph is an input) ----------------
__global__ void zero_int_kernel(int* __restrict__ p, int n){
  int i = blockIdx.x*256 + threadIdx.x;
  if (i < n) p[i] = 0;
}

__global__ void hist_kernel(const int* __restrict__ dst, int E, int* __restrict__ deg){
  int e = blockIdx.x*256 + threadIdx.x;
  if (e < E) atomicAdd(&deg[dst[e]], 1);
}

__global__ __launch_bounds__(1024)
void scanA_kernel(const int* __restrict__ deg, int n, int* __restrict__ rowptr, int* __restrict__ bsums){
  __shared__ int s[1024];
  int t = threadIdx.x;
  int i = blockIdx.x*1024 + t;
  int v = (i < n) ? deg[i] : 0;
  s[t] = v;
  __syncthreads();
  #pragma unroll
  for (int off = 1; off < 1024; off <<= 1){
    int a = (t >= off) ? s[t-off] : 0;
    __syncthreads();
    s[t] += a;
    __syncthreads();
  }
  if (i < n) rowptr[i] = s[t] - v;      // chunk-local exclusive
  if (t == 1023) bsums[blockIdx.x] = s[1023];
}

__global__ void scanB_kernel(const int* __restrict__ bsums, int nch, int* __restrict__ choff){
  int t = threadIdx.x;                   // 64 threads; nch <= 64 (49 here)
  int v = (t < nch) ? bsums[t] : 0;
  int x = v;
  #pragma unroll
  for (int off = 1; off < 64; off <<= 1){
    int u = __shfl_up(x, off, 64);
    if (t >= off) x += u;
  }
  choff[t] = x - v;                      // exclusive
}

__global__ __launch_bounds__(1024)
void scanC_kernel(const int* __restrict__ choff, int n, int* __restrict__ rowptr, int* __restrict__ cursor){
  int i = blockIdx.x*1024 + threadIdx.x;
  if (i < n){
    int r = rowptr[i] + choff[blockIdx.x];
    rowptr[i] = r;
    cursor[i] = r;
  }
}

__global__ void scatter_kernel(const int* __restrict__ src, const int* __restrict__ dst, int E,
                               int* __restrict__ cursor, int* __restrict__ adj){
  int e = blockIdx.x*256 + threadIdx.x;
  if (e < E){
    int pos = atomicAdd(&cursor[dst[e]], 1);
    adj[pos] = src[e];
  }
}

// ---------------- Prep: W transpose (fp32 [K][128] -> bf16 WT [128][K]) ----------------
struct PrepArgs {
  const float* w[12];
  unsigned short* o[12];
};

__global__ void transpose_w_kernel(PrepArgs a){
  int m = blockIdx.y;
  int K = (m < 4) ? 32 : 128;
  int halfK = K >> 1;
  int tot = 128 * halfK;                 // uint count
  int e = blockIdx.x*256 + threadIdx.x;
  if (e >= tot) return;
  int n  = e / halfK;
  int k2 = e % halfK;
  const float* W = a.w[m];
  unsigned int lo = __float_as_uint(W[(2*k2)  *128 + n]) >> 16;       // exact: bf16-grid values
  unsigned int hi = __float_as_uint(W[(2*k2+1)*128 + n]) & 0xffff0000u;
  ((unsigned int*)a.o[m])[e] = lo | hi;  // e == n*halfK + k2
}

__global__ void cvt_x_kernel(const float* __restrict__ x, unsigned short* __restrict__ xb, int n2){
  int i = blockIdx.x*256 + threadIdx.x;
  if (i < n2){
    float2 v = ((const float2*)x)[i];
    ((unsigned int*)xb)[i] = (__float_as_uint(v.x) >> 16) | (__float_as_uint(v.y) & 0xffff0000u);
  }
}

// ---------------- Fused 4-way projection GEMM via MFMA ----------------
// blockIdx.y = msel in {q,k,v,skip}. Block = 4 waves = 64 rows x 128 cols.
// WT bf16 [128][DIN] staged to LDS padded to DIN+8 (breaks pow-2 bank stride).
// Wave: 16 rows; A-frag A[m=lane&15][k=quad*8+j] 16B straight from global;
// 8 col-tiles x (DIN/32) k-steps of ds_read_b128 + mfma_f32_16x16x32_bf16.
template<int DIN>
__global__ __launch_bounds__(256)
void gemm4_mfma(const unsigned short* __restrict__ X, int nn,
                const unsigned short* __restrict__ T0, const unsigned short* __restrict__ T1,
                const unsigned short* __restrict__ T2, const unsigned short* __restrict__ T3,
                const float* __restrict__ b0, const float* __restrict__ b1,
                const float* __restrict__ b2, const float* __restrict__ b3,
                unsigned short* __restrict__ O0, unsigned short* __restrict__ O1,
                unsigned short* __restrict__ O2, unsigned short* __restrict__ O3)
{
  constexpr int KP = DIN + 8;            // padded row length (bf16 elems), 16B-multiple
  __shared__ __align__(16) unsigned short wt[128*KP];
  int t = threadIdx.x;
  int msel = blockIdx.y;
  const unsigned short* WT = (msel==0)?T0:(msel==1)?T1:(msel==2)?T2:T3;
  const float* B = (msel==0)?b0:(msel==1)?b1:(msel==2)?b2:b3;
  unsigned short* O = (msel==0)?O0:(msel==1)?O1:(msel==2)?O2:O3;

  { // stage WT dense [128][DIN] -> padded LDS [128][KP] (uint4 copies)
    const int NU = 128*DIN/8;
    for (int u = t; u < NU; u += 256){
      uint4 v = ((const uint4*)WT)[u];
      int n = u / (DIN/8), b = u % (DIN/8);
      *(uint4*)&wt[n*KP + b*8] = v;
    }
  }

  int lane = t & 63, wv = t >> 6;
  int m0 = blockIdx.x*64 + wv*16;
  int n16 = lane & 15, quad = lane >> 4;

  // A fragments (issued before the barrier; X rows padded in ws, never fault)
  bf16x8 af[DIN/32];
  {
    const unsigned short* xrow = X + (size_t)(m0 + n16)*DIN + quad*8;
    #pragma unroll
    for (int s = 0; s < DIN/32; s++) af[s] = *(const bf16x8*)(xrow + s*32);
  }

  __syncthreads();

  f32x4 acc[8];
  #pragma unroll
  for (int c=0;c<8;c++) acc[c] = (f32x4){0.f,0.f,0.f,0.f};

  #pragma unroll
  for (int s = 0; s < DIN/32; s++){
    #pragma unroll
    for (int c = 0; c < 8; c++){
      bf16x8 bf = *(const bf16x8*)&wt[(c*16 + n16)*KP + s*32 + quad*8];
      acc[c] = __builtin_amdgcn_mfma_f32_16x16x32_bf16(af[s], bf, acc[c], 0, 0, 0);
    }
  }

  // epilogue: + bias, bf16 store.  D: col = c*16 + (lane&15), row = m0 + quad*4 + r
  #pragma unroll
  for (int c = 0; c < 8; c++){
    int col = c*16 + n16;
    float bias = B[col];
    #pragma unroll
    for (int r = 0; r < 4; r++){
      int row = m0 + quad*4 + r;
      if (row < nn) O[(size_t)row*128 + col] = f2bs(acc[c][r] + bias);
    }
  }
}

// ---------------- Per-node attention, fused single pass ----------------
// Wave = one destination node. Lane holds channels c = 2*lane, 2*lane+1
// -> head = lane>>4; per-lane scalar online-softmax state. Groups of 4 edges:
// 8 independent row loads in flight. No LDS, no atomics.
__global__ __launch_bounds__(256)
void attn_kernel(const unsigned short* __restrict__ q,  const unsigned short* __restrict__ kmat,
                 const unsigned short* __restrict__ vmat, const unsigned short* __restrict__ skip,
                 const int* __restrict__ rowptr, const int* __restrict__ deg,
                 const int* __restrict__ adj, unsigned short* __restrict__ hout, int nn)
{
  int lane = threadIdx.x & 63, wid = threadIdx.x >> 6;
  int n = blockIdx.x*4 + wid;
  if (n >= nn) return;                   // wave-uniform
  const float RS = 0.17677669529663687f; // 1/sqrt(32)

  unsigned int qu = *(const unsigned int*)(q + (size_t)n*128 + 2*lane);
  float qx = bflo(qu), qy = bfhi(qu);
  int start = rowptr[n], dg = deg[n];
  float m = -INFINITY, l = 0.f, accx = 0.f, accy = 0.f;

  for (int c0 = 0; c0 < dg; c0 += 64){
    int cn = min(64, dg - c0);
    int idx = adj[start + c0 + min(lane, cn-1)];

    for (int g = 0; g < cn; g += 4){
      int gm = cn - g;
      int e1 = min(g+1, cn-1);
      int e2 = min(g+2, cn-1);
      int e3 = min(g+3, cn-1);
      int s0 = __shfl(idx, g , 64);
      int s1 = __shfl(idx, e1, 64);
      int s2 = __shfl(idx, e2, 64);
      int s3 = __shfl(idx, e3, 64);
      unsigned int ku0 = *(const unsigned int*)(kmat + (size_t)s0*128 + 2*lane);
      unsigned int ku1 = *(const unsigned int*)(kmat + (size_t)s1*128 + 2*lane);
      unsigned int ku2 = *(const unsigned int*)(kmat + (size_t)s2*128 + 2*lane);
      unsigned int ku3 = *(const unsigned int*)(kmat + (size_t)s3*128 + 2*lane);
      unsigned int vu0 = *(const unsigned int*)(vmat + (size_t)s0*128 + 2*lane);
      unsigned int vu1 = *(const unsigned int*)(vmat + (size_t)s1*128 + 2*lane);
      unsigned int vu2 = *(const unsigned int*)(vmat + (size_t)s2*128 + 2*lane);
      unsigned int vu3 = *(const unsigned int*)(vmat + (size_t)s3*128 + 2*lane);

      float p0 = qx*bflo(ku0) + qy*bfhi(ku0);
      float p1 = qx*bflo(ku1) + qy*bfhi(ku1);
      float p2 = qx*bflo(ku2) + qy*bfhi(ku2);
      float p3 = qx*bflo(ku3) + qy*bfhi(ku3);
      #pragma unroll
      for (int msk = 1; msk <= 8; msk <<= 1){
        p0 += __shfl_xor(p0, msk, 64);
        p1 += __shfl_xor(p1, msk, 64);
        p2 += __shfl_xor(p2, msk, 64);
        p3 += __shfl_xor(p3, msk, 64);
      }
      float f0 = p0*RS;
      float f1 = (gm > 1) ? p1*RS : -INFINITY;
      float f2 = (gm > 2) ? p2*RS : -INFINITY;
      float f3 = (gm > 3) ? p3*RS : -INFINITY;

      float gmax = fmaxf(fmaxf(f0,f1), fmaxf(f2,f3));
      float nm = fmaxf(m, gmax);
      float r  = __expf(m - nm);
      float w0 = __expf(f0 - nm);
      float w1 = __expf(f1 - nm);
      float w2 = __expf(f2 - nm);
      float w3 = __expf(f3 - nm);
      m = nm;
      l = l*r + ((w0+w1) + (w2+w3));
      accx = accx*r;
      accy = accy*r;
      accx = fmaf(w0, bflo(vu0), accx); accy = fmaf(w0, bfhi(vu0), accy);
      accx = fmaf(w1, bflo(vu1), accx); accy = fmaf(w1, bfhi(vu1), accy);
      accx = fmaf(w2, bflo(vu2), accx); accy = fmaf(w2, bfhi(vu2), accy);
      accx = fmaf(w3, bflo(vu3), accx); accy = fmaf(w3, bfhi(vu3), accy);
    }
  }

  float inv = (l > 0.f) ? 1.f/l : 0.f;   // deg==0 -> agg 0, matches reference
  unsigned int su = *(const unsigned int*)(skip + (size_t)n*128 + 2*lane);
  float ox = fmaxf(fmaf(accx, inv, bflo(su)), 0.f);
  float oy = fmaxf(fmaf(accy, inv, bfhi(su)), 0.f);
  unsigned int pk = (unsigned int)f2bs(ox) | ((unsigned int)f2bs(oy) << 16);
  *(unsigned int*)(hout + (size_t)n*128 + 2*lane) = pk; // own row; alias-safe
}

// ---------------- Output head: sigmoid(h @ Wf + bf); h bf16, Wf/bf fp32, out fp32 ----------------
__global__ __launch_bounds__(256)
void head_kernel(const unsigned short* __restrict__ h, const float* __restrict__ Wf,
                 const float* __restrict__ bfp, float* __restrict__ out, int nn)
{
  int lane = threadIdx.x & 63, wid = threadIdx.x >> 6;
  int n = blockIdx.x*4 + wid;
  if (n >= nn) return;
  unsigned int hu = *(const unsigned int*)(h + (size_t)n*128 + 2*lane);
  float2 wv = *(const float2*)(Wf + 2*lane);
  float p = bflo(hu)*wv.x + bfhi(hu)*wv.y;
  #pragma unroll
  for (int msk = 1; msk <= 32; msk <<= 1) p += __shfl_xor(p, msk, 64);
  if (lane == 0){
    float z = p + bfp[0];
    out[n] = 1.f / (1.f + __expf(-z));
  }
}

// ---------------- Launch ----------------
extern "C" void kernel_launch(void* const* d_in, const int* in_sizes, int n_in,
                              void* d_out, int out_size, void* d_ws, size_t ws_size,
                              hipStream_t stream) {
  const int N = in_sizes[0] / 32;
  const int E = in_sizes[1] / 2;
  const float* x = (const float*)d_in[0];       // fp32 (bf16-rounded values)
  const int* ei  = (const int*)d_in[1];
  const int* src = ei;
  const int* dst = ei + E;
  auto Wp = [&](int i){ return (const float*)d_in[i]; };
  const int NP = N + 64;                        // row padding for MFMA A-loads

  // workspace carve (~71 MB)
  char* p = (char*)d_ws;
  auto alloc = [&](size_t b){ char* r = p; p += (b + 255) & ~(size_t)255; return (void*)r; };
  unsigned short* F0 = (unsigned short*)alloc((size_t)NP*128*2);
  unsigned short* F1 = (unsigned short*)alloc((size_t)NP*128*2);
  unsigned short* Qb = (unsigned short*)alloc((size_t)NP*128*2);
  unsigned short* Kb = (unsigned short*)alloc((size_t)NP*128*2);
  unsigned short* Vb = (unsigned short*)alloc((size_t)NP*128*2);
  unsigned short* xb = (unsigned short*)alloc((size_t)NP*32*2);
  unsigned short* WT[12];
  for (int i = 0; i < 12; i++){
    int K = (i < 4) ? 32 : 128;
    WT[i] = (unsigned short*)alloc((size_t)128*K*2);
  }
  int* deg    = (int*)alloc((size_t)N*4);
  int* rowptr = (int*)alloc((size_t)N*4);
  int* cursor = (int*)alloc((size_t)N*4);
  int* adj    = (int*)alloc((size_t)E*4);
  int* bsums  = (int*)alloc(64*4);
  int* choff  = (int*)alloc(64*4);

  // CSR build
  zero_int_kernel<<<(N+255)/256, 256, 0, stream>>>(deg, N);
  hist_kernel<<<(E+255)/256, 256, 0, stream>>>(dst, E, deg);
  int nch = (N + 1023) / 1024;
  scanA_kernel<<<nch, 1024, 0, stream>>>(deg, N, rowptr, bsums);
  scanB_kernel<<<1, 64, 0, stream>>>(bsums, nch, choff);
  scanC_kernel<<<nch, 1024, 0, stream>>>(choff, N, rowptr, cursor);
  scatter_kernel<<<(E+255)/256, 256, 0, stream>>>(src, dst, E, cursor, adj);

  // prep: W transposes + x -> bf16
  PrepArgs pa;
  const int widx[12] = {2,4,6,8, 10,12,14,16, 18,20,22,24};
  for (int i = 0; i < 12; i++){ pa.w[i] = Wp(widx[i]); pa.o[i] = WT[i]; }
  transpose_w_kernel<<<dim3(32,12), 256, 0, stream>>>(pa);
  cvt_x_kernel<<<(N*16+255)/256, 256, 0, stream>>>(x, xb, N*16);

  dim3 gg((N+63)/64, 4);
  int ab = (N + 3) / 4;
  // layer 0 (din=32, A = xb): skip -> F0; attn in-place on F0
  gemm4_mfma<32><<<gg, 256, 0, stream>>>(xb, N,
      WT[0],WT[1],WT[2],WT[3], Wp(3),Wp(5),Wp(7),Wp(9), Qb,Kb,Vb, F0);
  attn_kernel<<<ab, 256, 0, stream>>>(Qb,Kb,Vb, F0, rowptr,deg,adj, F0, N);
  // layer 1 (din=128, A = F0): skip -> F1; attn in-place on F1
  gemm4_mfma<128><<<gg, 256, 0, stream>>>(F0, N,
      WT[4],WT[5],WT[6],WT[7], Wp(11),Wp(13),Wp(15),Wp(17), Qb,Kb,Vb, F1);
  attn_kernel<<<ab, 256, 0, stream>>>(Qb,Kb,Vb, F1, rowptr,deg,adj, F1, N);
  // layer 2 (din=128, A = F1): skip -> F0; attn in-place on F0
  gemm4_mfma<128><<<gg, 256, 0, stream>>>(F1, N,
      WT[8],WT[9],WT[10],WT[11], Wp(19),Wp(21),Wp(23),Wp(25), Qb,Kb,Vb, F0);
  attn_kernel<<<ab, 256, 0, stream>>>(Qb,Kb,Vb, F0, rowptr,deg,adj, F0, N);
  // head
  head_kernel<<<ab, 256, 0, stream>>>(F0, Wp(26), Wp(27), (float*)d_out, N);
}

// Round 6
// 472.739 us; speedup vs baseline: 2.2273x; 1.0208x over previous
//
#include <hip/hip_runtime.h>
#include <hip/hip_bf16.h>
#include <cstdint>
#include <cstddef>

typedef __attribute__((ext_vector_type(8))) short bf16x8;   // 8 bf16 = 4 VGPRs
typedef __attribute__((ext_vector_type(4))) float f32x4;    // MFMA acc

// ---- bf16-as-ushort helpers ----
__device__ __forceinline__ unsigned short f2bs(float f){
  __hip_bfloat16 h = __float2bfloat16(f);   // RNE
  return *(unsigned short*)&h;
}
__device__ __forceinline__ float bflo(unsigned int u){ return __uint_as_float(u << 16); }
__device__ __forceinline__ float bfhi(unsigned int u){ return __uint_as_float(u & 0xffff0000u); }
__device__ __forceinline__ void unp8(uint4 u, float* f){
  f[0]=bflo(u.x); f[1]=bfhi(u.x); f[2]=bflo(u.y); f[3]=bfhi(u.y);
  f[4]=bflo(u.z); f[5]=bfhi(u.z); f[6]=bflo(u.w); f[7]=bfhi(u.w);
}

// ---------------- CSR build (per call; graph is an input) ----------------
__global__ void zero_int_kernel(int* __restrict__ p, int n){
  int i = blockIdx.x*256 + threadIdx.x;
  if (i < n) p[i] = 0;
}

__global__ void hist_kernel(const int* __restrict__ dst, int E, int* __restrict__ deg){
  int e = blockIdx.x*256 + threadIdx.x;
  if (e < E) atomicAdd(&deg[dst[e]], 1);
}

__global__ __launch_bounds__(1024)
void scanA_kernel(const int* __restrict__ deg, int n, int* __restrict__ rowptr, int* __restrict__ bsums){
  __shared__ int s[1024];
  int t = threadIdx.x;
  int i = blockIdx.x*1024 + t;
  int v = (i < n) ? deg[i] : 0;
  s[t] = v;
  __syncthreads();
  #pragma unroll
  for (int off = 1; off < 1024; off <<= 1){
    int a = (t >= off) ? s[t-off] : 0;
    __syncthreads();
    s[t] += a;
    __syncthreads();
  }
  if (i < n) rowptr[i] = s[t] - v;      // chunk-local exclusive
  if (t == 1023) bsums[blockIdx.x] = s[1023];
}

__global__ void scanB_kernel(const int* __restrict__ bsums, int nch, int* __restrict__ choff){
  int t = threadIdx.x;                   // 64 threads; nch <= 64 (49 here)
  int v = (t < nch) ? bsums[t] : 0;
  int x = v;
  #pragma unroll
  for (int off = 1; off < 64; off <<= 1){
    int u = __shfl_up(x, off, 64);
    if (t >= off) x += u;
  }
  choff[t] = x - v;                      // exclusive
}

__global__ __launch_bounds__(1024)
void scanC_kernel(const int* __restrict__ choff, int n, int* __restrict__ rowptr, int* __restrict__ cursor){
  int i = blockIdx.x*1024 + threadIdx.x;
  if (i < n){
    int r = rowptr[i] + choff[blockIdx.x];
    rowptr[i] = r;
    cursor[i] = r;
  }
}

__global__ void scatter_kernel(const int* __restrict__ src, const int* __restrict__ dst, int E,
                               int* __restrict__ cursor, int* __restrict__ adj){
  int e = blockIdx.x*256 + threadIdx.x;
  if (e < E){
    int pos = atomicAdd(&cursor[dst[e]], 1);
    adj[pos] = src[e];
  }
}

// ---------------- Prep: W transpose (fp32 [K][128] -> bf16 WT [128][K]) ----------------
struct PrepArgs {
  const float* w[12];
  unsigned short* o[12];
};

__global__ void transpose_w_kernel(PrepArgs a){
  int m = blockIdx.y;
  int K = (m < 4) ? 32 : 128;
  int halfK = K >> 1;
  int tot = 128 * halfK;                 // uint count
  int e = blockIdx.x*256 + threadIdx.x;
  if (e >= tot) return;
  int n  = e / halfK;
  int k2 = e % halfK;
  const float* W = a.w[m];
  unsigned int lo = __float_as_uint(W[(2*k2)  *128 + n]) >> 16;       // exact: bf16-grid values
  unsigned int hi = __float_as_uint(W[(2*k2+1)*128 + n]) & 0xffff0000u;
  ((unsigned int*)a.o[m])[e] = lo | hi;  // e == n*halfK + k2
}

__global__ void cvt_x_kernel(const float* __restrict__ x, unsigned short* __restrict__ xb, int n2){
  int i = blockIdx.x*256 + threadIdx.x;
  if (i < n2){
    float2 v = ((const float2*)x)[i];
    ((unsigned int*)xb)[i] = (__float_as_uint(v.x) >> 16) | (__float_as_uint(v.y) & 0xffff0000u);
  }
}

// ---------------- Fused 4-way projection GEMM via MFMA ----------------
// blockIdx.y = msel in {q,k,v,skip}. Block = 4 waves = 64 rows x 128 cols.
// WT bf16 [128][DIN] staged to LDS padded to DIN+8.
// Wave: 16 rows; A-frag A[m=lane&15][k=quad*8+j] 16B straight from global;
// 8 col-tiles x (DIN/32) k-steps of ds_read_b128 + mfma_f32_16x16x32_bf16.
template<int DIN>
__global__ __launch_bounds__(256)
void gemm4_mfma(const unsigned short* __restrict__ X, int nn,
                const unsigned short* __restrict__ T0, const unsigned short* __restrict__ T1,
                const unsigned short* __restrict__ T2, const unsigned short* __restrict__ T3,
                const float* __restrict__ b0, const float* __restrict__ b1,
                const float* __restrict__ b2, const float* __restrict__ b3,
                unsigned short* __restrict__ O0, unsigned short* __restrict__ O1,
                unsigned short* __restrict__ O2, unsigned short* __restrict__ O3)
{
  constexpr int KP = DIN + 8;            // padded row length (bf16 elems), 16B-multiple
  __shared__ __align__(16) unsigned short wt[128*KP];
  int t = threadIdx.x;
  int msel = blockIdx.y;
  const unsigned short* WT = (msel==0)?T0:(msel==1)?T1:(msel==2)?T2:T3;
  const float* B = (msel==0)?b0:(msel==1)?b1:(msel==2)?b2:b3;
  unsigned short* O = (msel==0)?O0:(msel==1)?O1:(msel==2)?O2:O3;

  { // stage WT dense [128][DIN] -> padded LDS [128][KP] (uint4 copies)
    const int NU = 128*DIN/8;
    for (int u = t; u < NU; u += 256){
      uint4 v = ((const uint4*)WT)[u];
      int n = u / (DIN/8), b = u % (DIN/8);
      *(uint4*)&wt[n*KP + b*8] = v;
    }
  }

  int lane = t & 63, wv = t >> 6;
  int m0 = blockIdx.x*64 + wv*16;
  int n16 = lane & 15, quad = lane >> 4;

  // A fragments (issued before the barrier; X rows padded in ws, never fault)
  bf16x8 af[DIN/32];
  {
    const unsigned short* xrow = X + (size_t)(m0 + n16)*DIN + quad*8;
    #pragma unroll
    for (int s = 0; s < DIN/32; s++) af[s] = *(const bf16x8*)(xrow + s*32);
  }

  __syncthreads();

  f32x4 acc[8];
  #pragma unroll
  for (int c=0;c<8;c++) acc[c] = (f32x4){0.f,0.f,0.f,0.f};

  #pragma unroll
  for (int s = 0; s < DIN/32; s++){
    #pragma unroll
    for (int c = 0; c < 8; c++){
      bf16x8 bf = *(const bf16x8*)&wt[(c*16 + n16)*KP + s*32 + quad*8];
      acc[c] = __builtin_amdgcn_mfma_f32_16x16x32_bf16(af[s], bf, acc[c], 0, 0, 0);
    }
  }

  // epilogue: + bias, bf16 store.  D: col = c*16 + (lane&15), row = m0 + quad*4 + r
  #pragma unroll
  for (int c = 0; c < 8; c++){
    int col = c*16 + n16;
    float bias = B[col];
    #pragma unroll
    for (int r = 0; r < 4; r++){
      int row = m0 + quad*4 + r;
      if (row < nn) O[(size_t)row*128 + col] = f2bs(acc[c][r] + bias);
    }
  }
}

// ---------------- Per-node attention, group-per-edge layout ----------------
// Wave = one destination node. lane = (g,p): g=lane>>4 edge slot, p=lane&15
// owns channels 8p..8p+7 (all in head p>>2). Per iter: 4 edges (one per
// 16-lane group), each lane 1 k-dwordx4 + 1 v-dwordx4; dot reduced with
// xor1+xor2 only (lands each lane its OWN head's score). Per-lane online
// softmax over the group's edge subset; 4-way flash merge at node end.
// FINAL fuses the sigmoid head and writes d_out directly.
template<bool FINAL>
__global__ __launch_bounds__(256)
void attn_kernel(const unsigned short* __restrict__ q,  const unsigned short* __restrict__ kmat,
                 const unsigned short* __restrict__ vmat, const unsigned short* __restrict__ skip,
                 const int* __restrict__ rowptr, const int* __restrict__ deg,
                 const int* __restrict__ adj, unsigned short* __restrict__ hout,
                 const float* __restrict__ Wf, const float* __restrict__ bfp,
                 float* __restrict__ out, int nn)
{
  int lane = threadIdx.x & 63, wid = threadIdx.x >> 6;
  int n = blockIdx.x*4 + wid;
  if (n >= nn) return;                   // wave-uniform
  int p = lane & 15, g = lane >> 4;
  const float RS = 0.17677669529663687f; // 1/sqrt(32)

  float qf[8];
  { uint4 qu = *(const uint4*)(q + (size_t)n*128 + p*8); unp8(qu, qf); }

  int start = rowptr[n], dg = deg[n];
  float m = -INFINITY, l = 0.f;
  float acc[8];
  #pragma unroll
  for (int i=0;i<8;i++) acc[i]=0.f;

  for (int c0 = 0; c0 < dg; c0 += 64){
    int cn = min(64, dg - c0);
    int idx = adj[start + c0 + min(lane, cn-1)];
    int nit = (cn + 3) >> 2;

    bool val = g < cn;
    int s0 = __shfl(idx, min(g, cn-1), 64);
    uint4 ku = *(const uint4*)(kmat + (size_t)s0*128 + p*8);
    uint4 vu = *(const uint4*)(vmat + (size_t)s0*128 + p*8);

    for (int it = 0; it < nit; ++it){
      // prefetch next 4-edge slice (1-deep pipeline; 4 loads in flight)
      int j2 = (it+1)*4 + g;
      bool val2 = j2 < cn;
      int s2 = __shfl(idx, min(j2, cn-1), 64);
      uint4 ku2 = {0,0,0,0}, vu2 = {0,0,0,0};
      if (it + 1 < nit){                 // uniform branch
        ku2 = *(const uint4*)(kmat + (size_t)s2*128 + p*8);
        vu2 = *(const uint4*)(vmat + (size_t)s2*128 + p*8);
      }
      float kf[8]; unp8(ku, kf);
      float d = qf[0]*kf[0];
      #pragma unroll
      for (int i=1;i<8;i++) d = fmaf(qf[i], kf[i], d);
      d += __shfl_xor(d, 1, 64);         // stays within 16-lane group
      d += __shfl_xor(d, 2, 64);
      float f = val ? d*RS : -INFINITY;
      float nm = fmaxf(m, f);
      float r = __expf(fmaxf(m - nm, -80.f));   // clamp kills inf-inf NaN
      float w = __expf(fmaxf(f - nm, -80.f));
      m = nm;
      l = l*r + w;
      float vf[8]; unp8(vu, vf);
      #pragma unroll
      for (int i=0;i<8;i++) acc[i] = fmaf(w, vf[i], acc[i]*r);
      ku = ku2; vu = vu2; val = val2;
    }
  }

  // ---- merge the 4 per-group states (lane bits 4,5) ----
  float m1 = fmaxf(m, __shfl_xor(m, 16, 64));
  float M  = fmaxf(m1, __shfl_xor(m1, 32, 64));
  float sc = __expf(fmaxf(m - M, -80.f));
  float lp = l * sc;
  float l1 = lp + __shfl_xor(lp, 16, 64);
  float L  = l1 + __shfl_xor(l1, 32, 64);
  #pragma unroll
  for (int i=0;i<8;i++){
    float a = acc[i]*sc;
    a += __shfl_xor(a, 16, 64);
    a += __shfl_xor(a, 32, 64);
    acc[i] = a;
  }
  float inv = (L > 0.f) ? 1.f/L : 0.f;   // deg==0 -> agg 0, matches reference
  float sk[8];
  { uint4 su = *(const uint4*)(skip + (size_t)n*128 + p*8); unp8(su, sk); }
  float o[8];
  #pragma unroll
  for (int i=0;i<8;i++) o[i] = fmaxf(fmaf(acc[i], inv, sk[i]), 0.f);

  if constexpr (!FINAL){
    if (g == 0){                         // groups hold identical o after merge
      uint4 st;
      st.x = (unsigned)f2bs(o[0]) | ((unsigned)f2bs(o[1])<<16);
      st.y = (unsigned)f2bs(o[2]) | ((unsigned)f2bs(o[3])<<16);
      st.z = (unsigned)f2bs(o[4]) | ((unsigned)f2bs(o[5])<<16);
      st.w = (unsigned)f2bs(o[6]) | ((unsigned)f2bs(o[7])<<16);
      *(uint4*)(hout + (size_t)n*128 + p*8) = st;
    }
  } else {
    // fused head: sigmoid(o . Wf + bf)
    float4 w0 = *(const float4*)(Wf + p*8);
    float4 w1 = *(const float4*)(Wf + p*8 + 4);
    float pd = o[0]*w0.x;
    pd = fmaf(o[1], w0.y, pd); pd = fmaf(o[2], w0.z, pd); pd = fmaf(o[3], w0.w, pd);
    pd = fmaf(o[4], w1.x, pd); pd = fmaf(o[5], w1.y, pd);
    pd = fmaf(o[6], w1.z, pd); pd = fmaf(o[7], w1.w, pd);
    pd += __shfl_xor(pd, 1, 64);
    pd += __shfl_xor(pd, 2, 64);
    pd += __shfl_xor(pd, 4, 64);
    pd += __shfl_xor(pd, 8, 64);         // sum over p within group; o same all groups
    if (lane == 0){
      float z = pd + bfp[0];
      out[n] = 1.f / (1.f + __expf(-z));
    }
  }
}

// ---------------- Launch ----------------
extern "C" void kernel_launch(void* const* d_in, const int* in_sizes, int n_in,
                              void* d_out, int out_size, void* d_ws, size_t ws_size,
                              hipStream_t stream) {
  const int N = in_sizes[0] / 32;
  const int E = in_sizes[1] / 2;
  const float* x = (const float*)d_in[0];       // fp32 (bf16-rounded values)
  const int* ei  = (const int*)d_in[1];
  const int* src = ei;
  const int* dst = ei + E;
  auto Wp = [&](int i){ return (const float*)d_in[i]; };
  const int NP = N + 64;                        // row padding for MFMA A-loads

  // workspace carve (~71 MB)
  char* p = (char*)d_ws;
  auto alloc = [&](size_t b){ char* r = p; p += (b + 255) & ~(size_t)255; return (void*)r; };
  unsigned short* F0 = (unsigned short*)alloc((size_t)NP*128*2);
  unsigned short* F1 = (unsigned short*)alloc((size_t)NP*128*2);
  unsigned short* Qb = (unsigned short*)alloc((size_t)NP*128*2);
  unsigned short* Kb = (unsigned short*)alloc((size_t)NP*128*2);
  unsigned short* Vb = (unsigned short*)alloc((size_t)NP*128*2);
  unsigned short* xb = (unsigned short*)alloc((size_t)NP*32*2);
  unsigned short* WT[12];
  for (int i = 0; i < 12; i++){
    int K = (i < 4) ? 32 : 128;
    WT[i] = (unsigned short*)alloc((size_t)128*K*2);
  }
  int* deg    = (int*)alloc((size_t)N*4);
  int* rowptr = (int*)alloc((size_t)N*4);
  int* cursor = (int*)alloc((size_t)N*4);
  int* adj    = (int*)alloc((size_t)E*4);
  int* bsums  = (int*)alloc(64*4);
  int* choff  = (int*)alloc(64*4);

  // CSR build
  zero_int_kernel<<<(N+255)/256, 256, 0, stream>>>(deg, N);
  hist_kernel<<<(E+255)/256, 256, 0, stream>>>(dst, E, deg);
  int nch = (N + 1023) / 1024;
  scanA_kernel<<<nch, 1024, 0, stream>>>(deg, N, rowptr, bsums);
  scanB_kernel<<<1, 64, 0, stream>>>(bsums, nch, choff);
  scanC_kernel<<<nch, 1024, 0, stream>>>(choff, N, rowptr, cursor);
  scatter_kernel<<<(E+255)/256, 256, 0, stream>>>(src, dst, E, cursor, adj);

  // prep: W transposes + x -> bf16
  PrepArgs pa;
  const int widx[12] = {2,4,6,8, 10,12,14,16, 18,20,22,24};
  for (int i = 0; i < 12; i++){ pa.w[i] = Wp(widx[i]); pa.o[i] = WT[i]; }
  transpose_w_kernel<<<dim3(32,12), 256, 0, stream>>>(pa);
  cvt_x_kernel<<<(N*16+255)/256, 256, 0, stream>>>(x, xb, N*16);

  dim3 gg((N+63)/64, 4);
  int ab = (N + 3) / 4;
  // layer 0 (din=32, A = xb): skip -> F0; attn in-place on F0
  gemm4_mfma<32><<<gg, 256, 0, stream>>>(xb, N,
      WT[0],WT[1],WT[2],WT[3], Wp(3),Wp(5),Wp(7),Wp(9), Qb,Kb,Vb, F0);
  attn_kernel<false><<<ab, 256, 0, stream>>>(Qb,Kb,Vb, F0, rowptr,deg,adj, F0,
      nullptr, nullptr, nullptr, N);
  // layer 1 (din=128, A = F0): skip -> F1; attn in-place on F1
  gemm4_mfma<128><<<gg, 256, 0, stream>>>(F0, N,
      WT[4],WT[5],WT[6],WT[7], Wp(11),Wp(13),Wp(15),Wp(17), Qb,Kb,Vb, F1);
  attn_kernel<false><<<ab, 256, 0, stream>>>(Qb,Kb,Vb, F1, rowptr,deg,adj, F1,
      nullptr, nullptr, nullptr, N);
  // layer 2 (din=128, A = F1): skip -> F0; attn + fused sigmoid head -> d_out
  gemm4_mfma<128><<<gg, 256, 0, stream>>>(F1, N,
      WT[8],WT[9],WT[10],WT[11], Wp(19),Wp(21),Wp(23),Wp(25), Qb,Kb,Vb, F0);
  attn_kernel<true><<<ab, 256, 0, stream>>>(Qb,Kb,Vb, F0, rowptr,deg,adj, nullptr,
      Wp(26), Wp(27), (float*)d_out, N);
}